// Round 4
// baseline (2331.910 us; speedup 1.0000x reference)
//
#include <hip/hip_runtime.h>
#include <hip/hip_bf16.h>
#include <hip/hip_fp16.h>
#include <cstddef>

// GCN-LSTM decoder, N=50000, E=600000, H=O=128, S=8.
// Per step, FUSED kernel: each 128-node block (512 thr, 8 waves) aggregates
// A@h for its own 128 nodes directly into the LDS B-panel (gather from fp16
// h table), stages precomputed A@x half from global, one barrier, then the
// gate-packed MFMA GEMM + LSTM epilogue. Kills the 12.5K-block aggregate
// dispatch storm, the acb global round-trip, and overlaps gather latency
// with MFMA of the co-resident block (64KB LDS -> 2 blocks/CU).
// LDS B-panel: [8][128][32] bf16 with seg-XOR swizzle (seg ^= (row>>2)&3),
// 16B-aligned rows, 64KB total.

#define TPB 256
#define SWZ(row) (((row) >> 2) & 3)

typedef __attribute__((ext_vector_type(8))) short bf16x8;   // 8 bf16 = 4 VGPR
typedef __attribute__((ext_vector_type(4))) float f32x4;

__device__ __forceinline__ float sigf(float x) {
    return 1.0f / (1.0f + __expf(-x));
}
__device__ __forceinline__ float tanhfast(float x) {
    return 1.0f - 2.0f / (__expf(2.0f * x) + 1.0f);
}

// ---------------- CSR build ----------------

__global__ void k_hist(const int* __restrict__ dst, int* __restrict__ counts, int E) {
    int stride = gridDim.x * TPB;
    for (int e = blockIdx.x * TPB + threadIdx.x; e < E; e += stride)
        atomicAdd(&counts[dst[e]], 1);
}

__global__ void k_scan_block(const int* __restrict__ counts, int* __restrict__ offsets,
                             int* __restrict__ sums, int N) {
    __shared__ int s[TPB];
    int tid = threadIdx.x;
    int gid = blockIdx.x * TPB + tid;
    int v = (gid < N) ? counts[gid] : 0;
    s[tid] = v;
    __syncthreads();
    for (int d = 1; d < TPB; d <<= 1) {
        int t = (tid >= d) ? s[tid - d] : 0;
        __syncthreads();
        s[tid] += t;
        __syncthreads();
    }
    if (gid < N) offsets[gid] = s[tid] - v;
    if (tid == TPB - 1) sums[blockIdx.x] = s[tid];
}

__global__ void k_scan_tops(int* __restrict__ sums, int nb) {
    __shared__ int s[TPB];
    int tid = threadIdx.x;
    int v = (tid < nb) ? sums[tid] : 0;
    s[tid] = v;
    __syncthreads();
    for (int d = 1; d < TPB; d <<= 1) {
        int t = (tid >= d) ? s[tid - d] : 0;
        __syncthreads();
        s[tid] += t;
        __syncthreads();
    }
    if (tid < nb) sums[tid] = s[tid] - v;
}

__global__ void k_scan_finish(const int* __restrict__ counts, int* __restrict__ offsets,
                              const int* __restrict__ sums, int* __restrict__ cursor,
                              float* __restrict__ dinv, int N, int E) {
    int gid = blockIdx.x * TPB + threadIdx.x;
    if (gid < N) {
        int off = offsets[gid] + sums[blockIdx.x];
        offsets[gid] = off;
        cursor[gid]  = off;
        dinv[gid]    = rsqrtf((float)(counts[gid] + 1));
    }
    if (gid == 0) offsets[N] = E;
}

__global__ void k_csr_scatter(const int* __restrict__ src, const int* __restrict__ dst,
                              const float* __restrict__ dinv, int* __restrict__ cursor,
                              int2* __restrict__ csr_sw, int E) {
    int stride = gridDim.x * TPB;
    for (int e = blockIdx.x * TPB + threadIdx.x; e < E; e += stride) {
        int d = dst[e], s = src[e];
        int pos = atomicAdd(&cursor[d], 1);
        int2 r;
        r.x = s;
        r.y = __float_as_int(dinv[s] * dinv[d]);
        csr_sw[pos] = r;
    }
}

// ---------------- fp32 -> fp16 convert ----------------

__global__ void k_f32tof16(const float* __restrict__ in, __half* __restrict__ out, int n4) {
    int stride = gridDim.x * TPB;
    for (int i = blockIdx.x * TPB + threadIdx.x; i < n4; i += stride) {
        float4 v = ((const float4*)in)[i];
        __half2 lo = __floats2half2_rn(v.x, v.y);
        __half2 hi = __floats2half2_rn(v.z, v.w);
        ((__half2*)out)[2 * i]     = lo;
        ((__half2*)out)[2 * i + 1] = hi;
    }
}

// ---------------- dual aggregation (x and c): agg(bf16) = A_norm @ feat(fp16) ----------------
// One wave per node, grid-strided. Lane (g,t): g edge slot, t channel block.

union HU { f32x4 v; __half2 h[4]; };

__global__ __launch_bounds__(TPB) void k_aggregate_h2(
        const __half* __restrict__ fa, const __half* __restrict__ fb,
        __hip_bfloat16* __restrict__ aggA, __hip_bfloat16* __restrict__ aggB,
        const int* __restrict__ offsets, const int2* __restrict__ sw,
        const float* __restrict__ dinv, int N) {
    int wgid = blockIdx.x * 4 + (threadIdx.x >> 6);
    int nwaves = gridDim.x * 4;
    int lane = threadIdx.x & 63;
    int g = lane >> 4, t = lane & 15;
    const f32x4* fa4 = (const f32x4*)fa;
    const f32x4* fb4 = (const f32x4*)fb;

    for (int node = wgid; node < N; node += nwaves) {
        float accA[8], accB[8];
        #pragma unroll
        for (int j = 0; j < 8; ++j) { accA[j] = 0.f; accB[j] = 0.f; }

        int b = offsets[node], e = offsets[node + 1];
        for (int k = b; k < e; k += 4) {
            int kk = k + g;
            int kkc = (kk < e) ? kk : (e - 1);
            int2 sv = sw[kkc];
            float w = (kk < e) ? __int_as_float(sv.y) : 0.f;
            size_t ri = (size_t)sv.x * 16 + t;
            HU ua, ub;
            ua.v = fa4[ri];
            ub.v = fb4[ri];
            #pragma unroll
            for (int j = 0; j < 4; ++j) {
                float2 va = __half22float2(ua.h[j]);
                float2 vb = __half22float2(ub.h[j]);
                accA[2 * j]     = fmaf(w, va.x, accA[2 * j]);
                accA[2 * j + 1] = fmaf(w, va.y, accA[2 * j + 1]);
                accB[2 * j]     = fmaf(w, vb.x, accB[2 * j]);
                accB[2 * j + 1] = fmaf(w, vb.y, accB[2 * j + 1]);
            }
        }
        #pragma unroll
        for (int j = 0; j < 8; ++j) {
            accA[j] += __shfl_xor(accA[j], 16);
            accA[j] += __shfl_xor(accA[j], 32);
            accB[j] += __shfl_xor(accB[j], 16);
            accB[j] += __shfl_xor(accB[j], 32);
        }
        if (g == 0) {
            float di = dinv[node];
            float w0 = di * di;
            size_t ri = (size_t)node * 16 + t;
            HU ua, ub;
            ua.v = fa4[ri];
            ub.v = fb4[ri];
            union { f32x4 v; __hip_bfloat162 b2[4]; } oa, ob;
            #pragma unroll
            for (int j = 0; j < 4; ++j) {
                float2 va = __half22float2(ua.h[j]);
                float2 vb = __half22float2(ub.h[j]);
                oa.b2[j].x = __float2bfloat16(fmaf(w0, va.x, accA[2 * j]));
                oa.b2[j].y = __float2bfloat16(fmaf(w0, va.y, accA[2 * j + 1]));
                ob.b2[j].x = __float2bfloat16(fmaf(w0, vb.x, accB[2 * j]));
                ob.b2[j].y = __float2bfloat16(fmaf(w0, vb.y, accB[2 * j + 1]));
            }
            *(f32x4*)(aggA + (size_t)node * 128 + t * 8) = oa.v;
            *(f32x4*)(aggB + (size_t)node * 128 + t * 8) = ob.v;
        }
    }
}

// ---------------- weight packing into MFMA A-frag order ----------------

__global__ void k_pack_w128(const float* __restrict__ W, __hip_bfloat16* __restrict__ Wp) {
    int idx = blockIdx.x * TPB + threadIdx.x;     // 4*8*64*8 = 16384
    if (idx >= 16384) return;
    int j = idx & 7, lane = (idx >> 3) & 63, pblk = (idx >> 9) & 7, ks = idx >> 12;
    int k = ks * 32 + (lane >> 4) * 8 + j;
    int col = pblk * 16 + (lane & 15);
    Wp[idx] = __float2bfloat16(W[k * 128 + col]);
}

// cell weights: p = jcol*4 + gate  (gate order f,i,o,g matches bcell blocks)
__global__ void k_pack_wcell(const float* __restrict__ W, __hip_bfloat16* __restrict__ Wp, int S) {
    int total = S * 131072;
    int stride = gridDim.x * TPB;
    for (int idx = blockIdx.x * TPB + threadIdx.x; idx < total; idx += stride) {
        int j = idx & 7, lane = (idx >> 3) & 63, pblk = (idx >> 9) & 31;
        int ks = (idx >> 14) & 7, s = idx >> 17;
        int p = pblk * 16 + (lane & 15);
        int jcol = p >> 2, gate = p & 3;
        int k = ks * 32 + (lane >> 4) * 8 + j;
        Wp[idx] = __float2bfloat16(W[(size_t)s * 131072 + k * 512 + gate * 128 + jcol]);
    }
}

// ---------------- transposed MFMA GEMM: C[node][128] = agg @ W + b ----------------
// (for h0 / c0 only) Block: 128p x 128nodes, 4 waves 2x2.

__global__ __launch_bounds__(TPB) void k_gemm_t(
        const __hip_bfloat16* __restrict__ Ap,     // packed [4][8][64][8]
        const __hip_bfloat16* __restrict__ featb,  // [N][128] bf16
        const float* __restrict__ bias, float* __restrict__ Cout,
        __half* __restrict__ outh, int N) {
    __shared__ __align__(16) short Bs[128 * 40];   // stride 40
    int tid = threadIdx.x;
    int wave = tid >> 6, lane = tid & 63;
    int w_p = wave >> 1, w_n = wave & 1;
    int n0 = blockIdx.x * 128;
    int quad = lane >> 4, m16 = lane & 15;
    f32x4 zero = {0.f, 0.f, 0.f, 0.f};
    f32x4 acc[4][4];
    #pragma unroll
    for (int t = 0; t < 4; ++t)
        #pragma unroll
        for (int g = 0; g < 4; ++g) acc[t][g] = zero;

    for (int ks = 0; ks < 4; ++ks) {
        int kbase = ks * 32;
        __syncthreads();
        #pragma unroll
        for (int it = 0; it < 2; ++it) {
            int lin = it * TPB + tid;
            int row = lin >> 2, seg = lin & 3;
            int node = n0 + row;
            f32x4 v = zero;
            if (node < N) v = *(const f32x4*)(featb + (size_t)node * 128 + kbase + seg * 8);
            *(f32x4*)&Bs[row * 40 + seg * 8] = v;
        }
        __syncthreads();
        bf16x8 a[4], b[4];
        #pragma unroll
        for (int t = 0; t < 4; ++t)
            a[t] = *(const bf16x8*)(Ap + (((size_t)ks * 8 + w_p * 4 + t) * 64 + lane) * 8);
        #pragma unroll
        for (int g = 0; g < 4; ++g)
            b[g] = *(const bf16x8*)&Bs[(w_n * 64 + g * 16 + m16) * 40 + quad * 8];
        #pragma unroll
        for (int t = 0; t < 4; ++t)
            #pragma unroll
            for (int g = 0; g < 4; ++g)
                acc[t][g] = __builtin_amdgcn_mfma_f32_16x16x32_bf16(a[t], b[g], acc[t][g], 0, 0, 0);
    }
    #pragma unroll
    for (int t = 0; t < 4; ++t) {
        int p = w_p * 64 + t * 16 + quad * 4;
        f32x4 bv = *(const f32x4*)(bias + p);
        #pragma unroll
        for (int g = 0; g < 4; ++g) {
            int nd = n0 + w_n * 64 + g * 16 + m16;
            if (nd < N) {
                f32x4 o = acc[t][g] + bv;
                if (Cout) *(f32x4*)(Cout + (size_t)nd * 128 + p) = o;
                if (outh) {
                    __half2 lo = __floats2half2_rn(o.x, o.y);
                    __half2 hi = __floats2half2_rn(o.z, o.w);
                    __half2* hp = (__half2*)(outh + (size_t)nd * 128 + p);
                    hp[0] = lo;
                    hp[1] = hi;
                }
            }
        }
    }
}

// ---------------- FUSED step: aggregate(A@h) + cell GEMM + LSTM gates ----------------
// 512 threads, 8 waves. LDS B-panel [8][128][32] bf16 (64KB, seg-XOR swizzle).
// ks 0..3 = A@x (staged from global axb); ks 4..7 = A@h (gathered in-kernel).

__global__ __launch_bounds__(512, 4) void k_step_fused(
        const __hip_bfloat16* __restrict__ Ap,     // WcellP for this step [8][32][64][8]
        const __hip_bfloat16* __restrict__ axb,    // [N][128] bf16 (A@x)
        const __half* __restrict__ hin,            // [N][128] fp16 h_{s-1} gather source
        const int* __restrict__ offsets, const int2* __restrict__ sw,
        const float* __restrict__ dinv,
        const float* __restrict__ bias,            // bcell + s*512
        float* __restrict__ cbuf, float* __restrict__ hout,
        __half* __restrict__ houth,                // fp16 h_s (next step's gather source)
        float* __restrict__ hfin, int N) {
    __shared__ __align__(16) short Bs[8][128 * 32];
    int tid = threadIdx.x;
    int wave = tid >> 6, lane = tid & 63;
    int w_p = wave >> 2, w_n = wave & 3;           // placeholder, re-derived below
    // GEMM tiling: 4p x 2n waves
    w_p = wave >> 1;                               // 0..3 (16p units of 2)
    w_n = wave & 1;                                // 0..1 (64-node halves)
    int quad = lane >> 4, m16 = lane & 15;
    int n0 = blockIdx.x * 128;
    f32x4 zero = {0.f, 0.f, 0.f, 0.f};

    // ---- Phase A: stage A@x half (ks 0..3) from global ----
    {
        int row = tid >> 2, seg = tid & 3;
        int node = n0 + row;
        #pragma unroll
        for (int ks = 0; ks < 4; ++ks) {
            f32x4 v = zero;
            if (node < N) v = *(const f32x4*)(axb + (size_t)node * 128 + ks * 32 + seg * 8);
            *(f32x4*)&Bs[ks][row * 32 + ((seg ^ SWZ(row)) << 3)] = v;
        }
    }

    // ---- Phase B: aggregate A@h for this block's 128 nodes into ks 4..7 ----
    {
        const f32x4* f4 = (const f32x4*)hin;
        int g = quad, t = m16;
        for (int i = 0; i < 16; ++i) {
            int r = wave * 16 + i;
            int node = n0 + r;
            float acc[8];
            #pragma unroll
            for (int j = 0; j < 8; ++j) acc[j] = 0.f;
            if (node < N) {
                int b0 = offsets[node], e0 = offsets[node + 1];
                for (int k = b0; k < e0; k += 4) {
                    int kk = k + g;
                    int kkc = (kk < e0) ? kk : (e0 - 1);
                    int2 sv = sw[kkc];
                    float w = (kk < e0) ? __int_as_float(sv.y) : 0.f;
                    HU u;
                    u.v = f4[(size_t)sv.x * 16 + t];
                    #pragma unroll
                    for (int j = 0; j < 4; ++j) {
                        float2 vv = __half22float2(u.h[j]);
                        acc[2 * j]     = fmaf(w, vv.x, acc[2 * j]);
                        acc[2 * j + 1] = fmaf(w, vv.y, acc[2 * j + 1]);
                    }
                }
            }
            #pragma unroll
            for (int j = 0; j < 8; ++j) {
                acc[j] += __shfl_xor(acc[j], 16);
                acc[j] += __shfl_xor(acc[j], 32);
            }
            if (g == 0) {
                union { f32x4 v; __hip_bfloat162 b2[4]; } o;
                if (node < N) {
                    float di = dinv[node];
                    float w0 = di * di;
                    HU u;
                    u.v = f4[(size_t)node * 16 + t];
                    #pragma unroll
                    for (int j = 0; j < 4; ++j) {
                        float2 vv = __half22float2(u.h[j]);
                        o.b2[j].x = __float2bfloat16(fmaf(w0, vv.x, acc[2 * j]));
                        o.b2[j].y = __float2bfloat16(fmaf(w0, vv.y, acc[2 * j + 1]));
                    }
                } else {
                    o.v = zero;
                }
                int seg = t & 3;
                *(f32x4*)&Bs[4 + (t >> 2)][r * 32 + ((seg ^ SWZ(r)) << 3)] = o.v;
            }
        }
    }
    __syncthreads();

    // ---- Phase C: GEMM (K=256) + fused LSTM epilogue ----
    for (int p0i = 0; p0i < 4; ++p0i) {
        f32x4 acc[2][4];
        #pragma unroll
        for (int t = 0; t < 2; ++t)
            #pragma unroll
            for (int g = 0; g < 4; ++g) acc[t][g] = zero;

        #pragma unroll
        for (int ks = 0; ks < 8; ++ks) {
            bf16x8 a[2], b[4];
            #pragma unroll
            for (int t = 0; t < 2; ++t)
                a[t] = *(const bf16x8*)(Ap + (((size_t)ks * 32 + p0i * 8 + w_p * 2 + t) * 64 + lane) * 8);
            #pragma unroll
            for (int g = 0; g < 4; ++g) {
                int row = w_n * 64 + g * 16 + m16;
                b[g] = *(const bf16x8*)&Bs[ks][row * 32 + ((quad ^ SWZ(row)) << 3)];
            }
            #pragma unroll
            for (int t = 0; t < 2; ++t)
                #pragma unroll
                for (int g = 0; g < 4; ++g)
                    acc[t][g] = __builtin_amdgcn_mfma_f32_16x16x32_bf16(a[t], b[g], acc[t][g], 0, 0, 0);
        }

        #pragma unroll
        for (int t = 0; t < 2; ++t) {
            int p = p0i * 128 + (w_p * 2 + t) * 16 + quad * 4;
            int jcol = p >> 2;
            float bf = bias[jcol], bi = bias[128 + jcol], bo = bias[256 + jcol], bg = bias[384 + jcol];
            #pragma unroll
            for (int g = 0; g < 4; ++g) {
                int nd = n0 + w_n * 64 + g * 16 + m16;
                if (nd < N) {
                    float fv = sigf(acc[t][g].x + bf);
                    float iv = sigf(acc[t][g].y + bi);
                    float ov = sigf(acc[t][g].z + bo);
                    float gv = tanhfast(acc[t][g].w + bg);
                    size_t idx = (size_t)nd * 128 + jcol;
                    float cp = cbuf[idx];
                    float cn = fmaf(fv, cp, iv * gv);
                    cbuf[idx] = cn;
                    float hn = ov * tanhfast(cn);
                    hout[idx] = hn;
                    houth[idx] = __float2half(hn);
                    if (hfin) hfin[idx] = hn;
                }
            }
        }
    }
}

// ---------------- launch ----------------

extern "C" void kernel_launch(void* const* d_in, const int* in_sizes, int n_in,
                              void* d_out, int out_size, void* d_ws, size_t ws_size,
                              hipStream_t stream) {
    const float* x  = (const float*)d_in[0];
    const float* c  = (const float*)d_in[1];
    const int*   ei = (const int*)d_in[2];
    const float* Wh = (const float*)d_in[3];
    const float* bh = (const float*)d_in[4];
    const float* Wc = (const float*)d_in[5];
    const float* bc = (const float*)d_in[6];
    const float* Wcell = (const float*)d_in[7];
    const float* bcell = (const float*)d_in[8];
    float* out = (float*)d_out;

    const int N = in_sizes[0] / 128;
    const int E = in_sizes[2] / 2;
    const int S = in_sizes[7] / (256 * 512);
    const int* srcp = ei;
    const int* dstp = ei + E;

    // output layout: hs [S,N,128] | h_fin [N,128] | c_fin [N,128]
    float* hs   = out;
    float* hfin = out + (size_t)S * N * 128;
    float* cbuf = hfin + (size_t)N * 128;

    char* w = (char*)d_ws;
    size_t off = 0;
    auto alloc = [&](size_t bytes) -> void* {
        void* p = w + off;
        off += (bytes + 255) & ~(size_t)255;
        return p;
    };
    int*   counts  = (int*)alloc((size_t)N * 4);
    int*   offsets = (int*)alloc((size_t)(N + 1) * 4);
    int*   cursor  = (int*)alloc((size_t)N * 4);
    int*   sums    = (int*)alloc(256 * 4);
    int2*  csr_sw  = (int2*)alloc((size_t)E * 8);
    float* dinv    = (float*)alloc((size_t)N * 4);
    __hip_bfloat16* axb = (__hip_bfloat16*)alloc((size_t)N * 128 * 2);
    __hip_bfloat16* acb = (__hip_bfloat16*)alloc((size_t)N * 128 * 2);
    __half* xh  = (__half*)alloc((size_t)N * 128 * 2);
    __half* ch  = (__half*)alloc((size_t)N * 128 * 2);
    __half* hhA = (__half*)alloc((size_t)N * 128 * 2);   // fp16 h double buffer
    __half* hhB = (__half*)alloc((size_t)N * 128 * 2);
    __hip_bfloat16* WhP = (__hip_bfloat16*)alloc(16384 * 2);
    __hip_bfloat16* WcP = (__hip_bfloat16*)alloc(16384 * 2);
    __hip_bfloat16* WcellP = (__hip_bfloat16*)alloc((size_t)S * 131072 * 2);
    (void)ws_size; (void)n_in; (void)out_size;

    hipMemsetAsync(counts, 0, (size_t)N * 4, stream);
    int nb = (N + TPB - 1) / TPB;
    k_hist<<<1024, TPB, 0, stream>>>(dstp, counts, E);
    k_scan_block<<<nb, TPB, 0, stream>>>(counts, offsets, sums, N);
    k_scan_tops<<<1, TPB, 0, stream>>>(sums, nb);
    k_scan_finish<<<nb, TPB, 0, stream>>>(counts, offsets, sums, cursor, dinv, N, E);
    k_csr_scatter<<<1024, TPB, 0, stream>>>(srcp, dstp, dinv, cursor, csr_sw, E);

    // pack weights to MFMA frag order (bf16)
    k_pack_w128<<<64, TPB, 0, stream>>>(Wh, WhP);
    k_pack_w128<<<64, TPB, 0, stream>>>(Wc, WcP);
    k_pack_wcell<<<1024, TPB, 0, stream>>>(Wcell, WcellP, S);

    // fp16 gather sources for x and c
    int n4 = N * 128 / 4;
    k_f32tof16<<<1024, TPB, 0, stream>>>(x, xh, n4);
    k_f32tof16<<<1024, TPB, 0, stream>>>(c, ch, n4);

    int ngt = (N + 127) / 128;
    k_aggregate_h2<<<2048, TPB, 0, stream>>>(xh, ch, axb, acb, offsets, csr_sw, dinv, N);
    k_gemm_t<<<ngt, TPB, 0, stream>>>(WhP, axb, bh, nullptr, hhA, N);  // h0 -> fp16 only
    k_gemm_t<<<ngt, TPB, 0, stream>>>(WcP, acb, bc, cbuf, nullptr, N); // c0 -> fp32 cbuf

    __half* hin = hhA;
    __half* hnx = hhB;
    for (int s = 0; s < S; ++s) {
        k_step_fused<<<ngt, 512, 0, stream>>>(
            WcellP + (size_t)s * 131072, axb, hin, offsets, csr_sw, dinv,
            bcell + (size_t)s * 512, cbuf, hs + (size_t)s * N * 128, hnx,
            (s == S - 1) ? hfin : nullptr, N);
        __half* tmp = hin; hin = hnx; hnx = tmp;
    }
}

// Round 5
// 1282.576 us; speedup vs baseline: 1.8181x; 1.8181x over previous
//
#include <hip/hip_runtime.h>
#include <hip/hip_bf16.h>
#include <hip/hip_fp16.h>
#include <cstddef>

// GCN-LSTM decoder, N=50000, E=600000, H=O=128, S=8.
// GCN(feat,W,b) = (A_norm@feat)@W + b  (aggregate first, then GEMM).
// combined=[x,h] => A@combined = [A@x, A@h]; A@x precomputed once.
// GEMMs in bf16 MFMA (16x16x32), computed TRANSPOSED: C'[p][node]; cell GEMM
// gate-packed (p = jcol*4+gate) -> fused LSTM epilogue, no cross-lane traffic.
// Gather sources in fp16. Aggregate: lane (g,t)=(lane>>4,lane&15) gathers 16B
// (8 channels) of edge k+g; each wave interleaves TWO adjacent nodes
// (branchless zero-weight tails) -> 2 independent latency chains in flight.
// Cell GEMM: full 256-K B-panel staged once in 80KB LDS (1 barrier), p-blocks
// looped in-kernel. (R4's aggregate-into-GEMM fusion reverted: 64KB-LDS
// occupancy cap + one-shot grid serialized the gather at 2 blocks/CU.)

#define TPB 256

typedef __attribute__((ext_vector_type(8))) short bf16x8;   // 8 bf16 = 4 VGPR
typedef __attribute__((ext_vector_type(4))) float f32x4;

__device__ __forceinline__ float sigf(float x) {
    return 1.0f / (1.0f + __expf(-x));
}
__device__ __forceinline__ float tanhfast(float x) {
    return 1.0f - 2.0f / (__expf(2.0f * x) + 1.0f);
}

// ---------------- CSR build ----------------

__global__ void k_hist(const int* __restrict__ dst, int* __restrict__ counts, int E) {
    int stride = gridDim.x * TPB;
    for (int e = blockIdx.x * TPB + threadIdx.x; e < E; e += stride)
        atomicAdd(&counts[dst[e]], 1);
}

__global__ void k_scan_block(const int* __restrict__ counts, int* __restrict__ offsets,
                             int* __restrict__ sums, int N) {
    __shared__ int s[TPB];
    int tid = threadIdx.x;
    int gid = blockIdx.x * TPB + tid;
    int v = (gid < N) ? counts[gid] : 0;
    s[tid] = v;
    __syncthreads();
    for (int d = 1; d < TPB; d <<= 1) {
        int t = (tid >= d) ? s[tid - d] : 0;
        __syncthreads();
        s[tid] += t;
        __syncthreads();
    }
    if (gid < N) offsets[gid] = s[tid] - v;
    if (tid == TPB - 1) sums[blockIdx.x] = s[tid];
}

__global__ void k_scan_tops(int* __restrict__ sums, int nb) {
    __shared__ int s[TPB];
    int tid = threadIdx.x;
    int v = (tid < nb) ? sums[tid] : 0;
    s[tid] = v;
    __syncthreads();
    for (int d = 1; d < TPB; d <<= 1) {
        int t = (tid >= d) ? s[tid - d] : 0;
        __syncthreads();
        s[tid] += t;
        __syncthreads();
    }
    if (tid < nb) sums[tid] = s[tid] - v;
}

__global__ void k_scan_finish(const int* __restrict__ counts, int* __restrict__ offsets,
                              const int* __restrict__ sums, int* __restrict__ cursor,
                              float* __restrict__ dinv, int N, int E) {
    int gid = blockIdx.x * TPB + threadIdx.x;
    if (gid < N) {
        int off = offsets[gid] + sums[blockIdx.x];
        offsets[gid] = off;
        cursor[gid]  = off;
        dinv[gid]    = rsqrtf((float)(counts[gid] + 1));
    }
    if (gid == 0) offsets[N] = E;
}

__global__ void k_csr_scatter(const int* __restrict__ src, const int* __restrict__ dst,
                              const float* __restrict__ dinv, int* __restrict__ cursor,
                              int2* __restrict__ csr_sw, int E) {
    int stride = gridDim.x * TPB;
    for (int e = blockIdx.x * TPB + threadIdx.x; e < E; e += stride) {
        int d = dst[e], s = src[e];
        int pos = atomicAdd(&cursor[d], 1);
        int2 r;
        r.x = s;
        r.y = __float_as_int(dinv[s] * dinv[d]);
        csr_sw[pos] = r;
    }
}

// ---------------- fp32 -> fp16 convert (x and c in one launch) ----------------

__global__ void k_f32tof16_2(const float* __restrict__ a, const float* __restrict__ b,
                             __half* __restrict__ oa, __half* __restrict__ ob, int n4) {
    int stride = gridDim.x * TPB;
    for (int i = blockIdx.x * TPB + threadIdx.x; i < n4; i += stride) {
        float4 va = ((const float4*)a)[i];
        float4 vb = ((const float4*)b)[i];
        ((__half2*)oa)[2 * i]     = __floats2half2_rn(va.x, va.y);
        ((__half2*)oa)[2 * i + 1] = __floats2half2_rn(va.z, va.w);
        ((__half2*)ob)[2 * i]     = __floats2half2_rn(vb.x, vb.y);
        ((__half2*)ob)[2 * i + 1] = __floats2half2_rn(vb.z, vb.w);
    }
}

// ---------------- aggregation: agg(bf16) = A_norm @ feat(fp16) ----------------
// One wave per TWO adjacent nodes, grid-strided. Lane (g,t): g edge slot,
// t channel block. Branchless bodies (clamped index, zero weight past end).

union HU { f32x4 v; __half2 h[4]; };

__global__ __launch_bounds__(TPB) void k_aggregate_h(
        const __half* __restrict__ feat, __hip_bfloat16* __restrict__ agg,
        const int* __restrict__ offsets, const int2* __restrict__ sw,
        const float* __restrict__ dinv, int N) {
    int wid = blockIdx.x * 4 + (threadIdx.x >> 6);
    int nw = gridDim.x * 4;
    int lane = threadIdx.x & 63;
    int g = lane >> 4, t = lane & 15;
    const f32x4* f4 = (const f32x4*)feat;

    for (int n0 = wid * 2; n0 < N; n0 += nw * 2) {
        int n1 = n0 + 1;
        bool has1 = (n1 < N);
        int b0 = offsets[n0], e0 = offsets[n0 + 1];
        int b1 = has1 ? offsets[n1] : 0;
        int e1 = has1 ? offsets[n1 + 1] : 0;
        int s0 = (e0 > b0) ? e0 - 1 : 0;
        int s1 = (e1 > b1) ? e1 - 1 : 0;
        int it0 = (e0 - b0 + 3) >> 2;
        int it1 = (e1 - b1 + 3) >> 2;
        int nit = it0 > it1 ? it0 : it1;

        float acc0[8], acc1[8];
        #pragma unroll
        for (int j = 0; j < 8; ++j) { acc0[j] = 0.f; acc1[j] = 0.f; }

        for (int i = 0; i < nit; ++i) {
            int kk0 = b0 + 4 * i + g;
            int kc0 = (kk0 < e0) ? kk0 : s0;
            int kk1 = b1 + 4 * i + g;
            int kc1 = (kk1 < e1) ? kk1 : s1;
            int2 v0 = sw[kc0];
            int2 v1 = sw[kc1];
            float w0 = (kk0 < e0) ? __int_as_float(v0.y) : 0.f;
            float w1 = (kk1 < e1) ? __int_as_float(v1.y) : 0.f;
            HU u0, u1;
            u0.v = f4[(size_t)v0.x * 16 + t];
            u1.v = f4[(size_t)v1.x * 16 + t];
            #pragma unroll
            for (int j = 0; j < 4; ++j) {
                float2 p0 = __half22float2(u0.h[j]);
                float2 p1 = __half22float2(u1.h[j]);
                acc0[2 * j]     = fmaf(w0, p0.x, acc0[2 * j]);
                acc0[2 * j + 1] = fmaf(w0, p0.y, acc0[2 * j + 1]);
                acc1[2 * j]     = fmaf(w1, p1.x, acc1[2 * j]);
                acc1[2 * j + 1] = fmaf(w1, p1.y, acc1[2 * j + 1]);
            }
        }
        #pragma unroll
        for (int j = 0; j < 8; ++j) {
            acc0[j] += __shfl_xor(acc0[j], 16);
            acc0[j] += __shfl_xor(acc0[j], 32);
            acc1[j] += __shfl_xor(acc1[j], 16);
            acc1[j] += __shfl_xor(acc1[j], 32);
        }
        if (g == 0) {
            {
                float di = dinv[n0];
                float w0 = di * di;
                HU u;
                u.v = f4[(size_t)n0 * 16 + t];
                union { f32x4 v; __hip_bfloat162 b2[4]; } o;
                #pragma unroll
                for (int j = 0; j < 4; ++j) {
                    float2 vv = __half22float2(u.h[j]);
                    o.b2[j].x = __float2bfloat16(fmaf(w0, vv.x, acc0[2 * j]));
                    o.b2[j].y = __float2bfloat16(fmaf(w0, vv.y, acc0[2 * j + 1]));
                }
                *(f32x4*)(agg + (size_t)n0 * 128 + t * 8) = o.v;
            }
            if (has1) {
                float di = dinv[n1];
                float w0 = di * di;
                HU u;
                u.v = f4[(size_t)n1 * 16 + t];
                union { f32x4 v; __hip_bfloat162 b2[4]; } o;
                #pragma unroll
                for (int j = 0; j < 4; ++j) {
                    float2 vv = __half22float2(u.h[j]);
                    o.b2[j].x = __float2bfloat16(fmaf(w0, vv.x, acc1[2 * j]));
                    o.b2[j].y = __float2bfloat16(fmaf(w0, vv.y, acc1[2 * j + 1]));
                }
                *(f32x4*)(agg + (size_t)n1 * 128 + t * 8) = o.v;
            }
        }
    }
}

// dual-source aggregate (x and c share the CSR stream), grid-strided
__global__ __launch_bounds__(TPB) void k_aggregate_h2(
        const __half* __restrict__ fa, const __half* __restrict__ fb,
        __hip_bfloat16* __restrict__ aggA, __hip_bfloat16* __restrict__ aggB,
        const int* __restrict__ offsets, const int2* __restrict__ sw,
        const float* __restrict__ dinv, int N) {
    int wgid = blockIdx.x * 4 + (threadIdx.x >> 6);
    int nwaves = gridDim.x * 4;
    int lane = threadIdx.x & 63;
    int g = lane >> 4, t = lane & 15;
    const f32x4* fa4 = (const f32x4*)fa;
    const f32x4* fb4 = (const f32x4*)fb;

    for (int node = wgid; node < N; node += nwaves) {
        float accA[8], accB[8];
        #pragma unroll
        for (int j = 0; j < 8; ++j) { accA[j] = 0.f; accB[j] = 0.f; }

        int b = offsets[node], e = offsets[node + 1];
        for (int k = b; k < e; k += 4) {
            int kk = k + g;
            int kkc = (kk < e) ? kk : (e - 1);
            int2 sv = sw[kkc];
            float w = (kk < e) ? __int_as_float(sv.y) : 0.f;
            size_t ri = (size_t)sv.x * 16 + t;
            HU ua, ub;
            ua.v = fa4[ri];
            ub.v = fb4[ri];
            #pragma unroll
            for (int j = 0; j < 4; ++j) {
                float2 va = __half22float2(ua.h[j]);
                float2 vb = __half22float2(ub.h[j]);
                accA[2 * j]     = fmaf(w, va.x, accA[2 * j]);
                accA[2 * j + 1] = fmaf(w, va.y, accA[2 * j + 1]);
                accB[2 * j]     = fmaf(w, vb.x, accB[2 * j]);
                accB[2 * j + 1] = fmaf(w, vb.y, accB[2 * j + 1]);
            }
        }
        #pragma unroll
        for (int j = 0; j < 8; ++j) {
            accA[j] += __shfl_xor(accA[j], 16);
            accA[j] += __shfl_xor(accA[j], 32);
            accB[j] += __shfl_xor(accB[j], 16);
            accB[j] += __shfl_xor(accB[j], 32);
        }
        if (g == 0) {
            float di = dinv[node];
            float w0 = di * di;
            size_t ri = (size_t)node * 16 + t;
            HU ua, ub;
            ua.v = fa4[ri];
            ub.v = fb4[ri];
            union { f32x4 v; __hip_bfloat162 b2[4]; } oa, ob;
            #pragma unroll
            for (int j = 0; j < 4; ++j) {
                float2 va = __half22float2(ua.h[j]);
                float2 vb = __half22float2(ub.h[j]);
                oa.b2[j].x = __float2bfloat16(fmaf(w0, va.x, accA[2 * j]));
                oa.b2[j].y = __float2bfloat16(fmaf(w0, va.y, accA[2 * j + 1]));
                ob.b2[j].x = __float2bfloat16(fmaf(w0, vb.x, accB[2 * j]));
                ob.b2[j].y = __float2bfloat16(fmaf(w0, vb.y, accB[2 * j + 1]));
            }
            *(f32x4*)(aggA + (size_t)node * 128 + t * 8) = oa.v;
            *(f32x4*)(aggB + (size_t)node * 128 + t * 8) = ob.v;
        }
    }
}

// ---------------- weight packing into MFMA A-frag order ----------------
// Layout: Wp[ks][pblk][lane][j] = W'[pblk*16 + (lane&15)][ks*32 + (lane>>4)*8 + j]
// Packs Wh and Wc in one launch (idx < 16384 -> Wh, else Wc).

__global__ void k_pack_w128_2(const float* __restrict__ Wh, const float* __restrict__ Wc,
                              __hip_bfloat16* __restrict__ WhP, __hip_bfloat16* __restrict__ WcP) {
    int gid = blockIdx.x * TPB + threadIdx.x;     // 2*16384
    if (gid >= 32768) return;
    const float* W = (gid < 16384) ? Wh : Wc;
    __hip_bfloat16* Wp = (gid < 16384) ? WhP : WcP;
    int idx = gid & 16383;
    int j = idx & 7, lane = (idx >> 3) & 63, pblk = (idx >> 9) & 7, ks = idx >> 12;
    int k = ks * 32 + (lane >> 4) * 8 + j;
    int col = pblk * 16 + (lane & 15);
    Wp[idx] = __float2bfloat16(W[k * 128 + col]);
}

// cell weights: p = jcol*4 + gate  (gate order f,i,o,g matches bcell blocks)
__global__ void k_pack_wcell(const float* __restrict__ W, __hip_bfloat16* __restrict__ Wp, int S) {
    int total = S * 131072;
    int stride = gridDim.x * TPB;
    for (int idx = blockIdx.x * TPB + threadIdx.x; idx < total; idx += stride) {
        int j = idx & 7, lane = (idx >> 3) & 63, pblk = (idx >> 9) & 31;
        int ks = (idx >> 14) & 7, s = idx >> 17;
        int p = pblk * 16 + (lane & 15);
        int jcol = p >> 2, gate = p & 3;
        int k = ks * 32 + (lane >> 4) * 8 + j;
        Wp[idx] = __float2bfloat16(W[(size_t)s * 131072 + k * 512 + gate * 128 + jcol]);
    }
}

// ---------------- transposed MFMA GEMM: C[node][128] = agg @ W + b ----------------
// M = 128 weight cols (p), N-dim = nodes. Block: 128p x 128nodes, 4 waves 2x2.
// Cout (fp32) and outh (fp16) independently nullable.

__global__ __launch_bounds__(TPB) void k_gemm_t(
        const __hip_bfloat16* __restrict__ Ap,     // packed [4][8][64][8]
        const __hip_bfloat16* __restrict__ featb,  // [N][128] bf16
        const float* __restrict__ bias, float* __restrict__ Cout,
        __half* __restrict__ outh, int N) {
    __shared__ __align__(16) short Bs[128 * 40];   // 128 nodes x 32 bf16, stride 40
    int tid = threadIdx.x;
    int wave = tid >> 6, lane = tid & 63;
    int w_p = wave >> 1, w_n = wave & 1;
    int n0 = blockIdx.x * 128;
    int quad = lane >> 4, m16 = lane & 15;
    f32x4 zero = {0.f, 0.f, 0.f, 0.f};
    f32x4 acc[4][4];
    #pragma unroll
    for (int t = 0; t < 4; ++t)
        #pragma unroll
        for (int g = 0; g < 4; ++g) acc[t][g] = zero;

    for (int ks = 0; ks < 4; ++ks) {
        int kbase = ks * 32;
        __syncthreads();
        #pragma unroll
        for (int it = 0; it < 2; ++it) {
            int lin = it * TPB + tid;
            int row = lin >> 2, seg = lin & 3;
            int node = n0 + row;
            f32x4 v = zero;
            if (node < N) v = *(const f32x4*)(featb + (size_t)node * 128 + kbase + seg * 8);
            *(f32x4*)&Bs[row * 40 + seg * 8] = v;
        }
        __syncthreads();
        bf16x8 a[4], b[4];
        #pragma unroll
        for (int t = 0; t < 4; ++t)
            a[t] = *(const bf16x8*)(Ap + (((size_t)ks * 8 + w_p * 4 + t) * 64 + lane) * 8);
        #pragma unroll
        for (int g = 0; g < 4; ++g)
            b[g] = *(const bf16x8*)&Bs[(w_n * 64 + g * 16 + m16) * 40 + quad * 8];
        #pragma unroll
        for (int t = 0; t < 4; ++t)
            #pragma unroll
            for (int g = 0; g < 4; ++g)
                acc[t][g] = __builtin_amdgcn_mfma_f32_16x16x32_bf16(a[t], b[g], acc[t][g], 0, 0, 0);
    }
    #pragma unroll
    for (int t = 0; t < 4; ++t) {
        int p = w_p * 64 + t * 16 + quad * 4;
        f32x4 bv = *(const f32x4*)(bias + p);
        #pragma unroll
        for (int g = 0; g < 4; ++g) {
            int nd = n0 + w_n * 64 + g * 16 + m16;
            if (nd < N) {
                f32x4 o = acc[t][g] + bv;
                if (Cout) *(f32x4*)(Cout + (size_t)nd * 128 + p) = o;
                if (outh) {
                    __half2 lo = __floats2half2_rn(o.x, o.y);
                    __half2 hi = __floats2half2_rn(o.z, o.w);
                    __half2* hp = (__half2*)(outh + (size_t)nd * 128 + p);
                    hp[0] = lo;
                    hp[1] = hi;
                }
            }
        }
    }
}

// ---------------- fused cell GEMM + LSTM gates (transposed, gate-packed) ----------------
// C'[p][node], p = jcol*4+gate, K=256 (ax | ah). Lane reg r = gate r of jcol.
// Full K=256 B-panel staged once (80 KB LDS, ONE barrier); p-blocks looped in-kernel.

__global__ __launch_bounds__(TPB) void k_cell_t(
        const __hip_bfloat16* __restrict__ Ap,     // packed [8][32][64][8] for this step
        const __hip_bfloat16* __restrict__ axb, const __hip_bfloat16* __restrict__ ahb,
        const float* __restrict__ bias,            // bcell + s*512
        float* __restrict__ cbuf, float* __restrict__ hout,
        __half* __restrict__ houth,                // fp16 copy of h for next aggregate
        float* __restrict__ hfin, int N) {
    __shared__ __align__(16) short Bs[8][128 * 40];   // 8 K-chunks x (128 nodes x 32 bf16, stride 40)
    int tid = threadIdx.x;
    int wave = tid >> 6, lane = tid & 63;
    int w_p = wave >> 1, w_n = wave & 1;
    int n0 = blockIdx.x * 128;
    int quad = lane >> 4, m16 = lane & 15;
    f32x4 zero = {0.f, 0.f, 0.f, 0.f};

    // stage entire 128-node x 256-K panel, one barrier
    #pragma unroll
    for (int it = 0; it < 16; ++it) {
        int ks = it >> 1;
        int lin = ((it & 1) << 8) + tid;           // 0..511
        int row = lin >> 2, seg = lin & 3;
        const __hip_bfloat16* fsrc = (ks < 4) ? axb : ahb;
        int node = n0 + row;
        f32x4 v = zero;
        if (node < N) v = *(const f32x4*)(fsrc + (size_t)node * 128 + (ks & 3) * 32 + seg * 8);
        *(f32x4*)&Bs[ks][row * 40 + seg * 8] = v;
    }
    __syncthreads();

    for (int p0i = 0; p0i < 4; ++p0i) {
        f32x4 acc[4][4];
        #pragma unroll
        for (int t = 0; t < 4; ++t)
            #pragma unroll
            for (int g = 0; g < 4; ++g) acc[t][g] = zero;

        #pragma unroll
        for (int ks = 0; ks < 8; ++ks) {
            bf16x8 a[4], b[4];
            #pragma unroll
            for (int t = 0; t < 4; ++t)
                a[t] = *(const bf16x8*)(Ap + (((size_t)ks * 32 + p0i * 8 + w_p * 4 + t) * 64 + lane) * 8);
            #pragma unroll
            for (int g = 0; g < 4; ++g)
                b[g] = *(const bf16x8*)&Bs[ks][(w_n * 64 + g * 16 + m16) * 40 + quad * 8];
            #pragma unroll
            for (int t = 0; t < 4; ++t)
                #pragma unroll
                for (int g = 0; g < 4; ++g)
                    acc[t][g] = __builtin_amdgcn_mfma_f32_16x16x32_bf16(a[t], b[g], acc[t][g], 0, 0, 0);
        }

        #pragma unroll
        for (int t = 0; t < 4; ++t) {
            int p = p0i * 128 + w_p * 64 + t * 16 + quad * 4;
            int jcol = p >> 2;
            float bf = bias[jcol], bi = bias[128 + jcol], bo = bias[256 + jcol], bg = bias[384 + jcol];
            #pragma unroll
            for (int g = 0; g < 4; ++g) {
                int nd = n0 + w_n * 64 + g * 16 + m16;
                if (nd < N) {
                    float fv = sigf(acc[t][g].x + bf);
                    float iv = sigf(acc[t][g].y + bi);
                    float ov = sigf(acc[t][g].z + bo);
                    float gv = tanhfast(acc[t][g].w + bg);
                    size_t idx = (size_t)nd * 128 + jcol;
                    float cp = cbuf[idx];
                    float cn = fmaf(fv, cp, iv * gv);
                    cbuf[idx] = cn;
                    float hn = ov * tanhfast(cn);
                    hout[idx] = hn;
                    houth[idx] = __float2half(hn);
                    if (hfin) hfin[idx] = hn;
                }
            }
        }
    }
}

// ---------------- launch ----------------

extern "C" void kernel_launch(void* const* d_in, const int* in_sizes, int n_in,
                              void* d_out, int out_size, void* d_ws, size_t ws_size,
                              hipStream_t stream) {
    const float* x  = (const float*)d_in[0];
    const float* c  = (const float*)d_in[1];
    const int*   ei = (const int*)d_in[2];
    const float* Wh = (const float*)d_in[3];
    const float* bh = (const float*)d_in[4];
    const float* Wc = (const float*)d_in[5];
    const float* bc = (const float*)d_in[6];
    const float* Wcell = (const float*)d_in[7];
    const float* bcell = (const float*)d_in[8];
    float* out = (float*)d_out;

    const int N = in_sizes[0] / 128;
    const int E = in_sizes[2] / 2;
    const int S = in_sizes[7] / (256 * 512);
    const int* srcp = ei;
    const int* dstp = ei + E;

    // output layout: hs [S,N,128] | h_fin [N,128] | c_fin [N,128]
    float* hs   = out;
    float* hfin = out + (size_t)S * N * 128;
    float* cbuf = hfin + (size_t)N * 128;

    char* w = (char*)d_ws;
    size_t off = 0;
    auto alloc = [&](size_t bytes) -> void* {
        void* p = w + off;
        off += (bytes + 255) & ~(size_t)255;
        return p;
    };
    int*   counts  = (int*)alloc((size_t)N * 4);
    int*   offsets = (int*)alloc((size_t)(N + 1) * 4);
    int*   cursor  = (int*)alloc((size_t)N * 4);
    int*   sums    = (int*)alloc(256 * 4);
    int2*  csr_sw  = (int2*)alloc((size_t)E * 8);
    float* dinv    = (float*)alloc((size_t)N * 4);
    __hip_bfloat16* axb = (__hip_bfloat16*)alloc((size_t)N * 128 * 2);
    __hip_bfloat16* acb = (__hip_bfloat16*)alloc((size_t)N * 128 * 2);  // ac, then ah per step
    __half* xh = (__half*)alloc((size_t)N * 128 * 2);
    __half* ch = (__half*)alloc((size_t)N * 128 * 2);
    __half* hh = (__half*)alloc((size_t)N * 128 * 2);   // fp16 h (h0, then h_s)
    __hip_bfloat16* WhP = (__hip_bfloat16*)alloc(16384 * 2);
    __hip_bfloat16* WcP = (__hip_bfloat16*)alloc(16384 * 2);
    __hip_bfloat16* WcellP = (__hip_bfloat16*)alloc((size_t)S * 131072 * 2);
    (void)ws_size; (void)n_in; (void)out_size;

    hipMemsetAsync(counts, 0, (size_t)N * 4, stream);
    int nb = (N + TPB - 1) / TPB;
    k_hist<<<1024, TPB, 0, stream>>>(dstp, counts, E);
    k_scan_block<<<nb, TPB, 0, stream>>>(counts, offsets, sums, N);
    k_scan_tops<<<1, TPB, 0, stream>>>(sums, nb);
    k_scan_finish<<<nb, TPB, 0, stream>>>(counts, offsets, sums, cursor, dinv, N, E);
    k_csr_scatter<<<1024, TPB, 0, stream>>>(srcp, dstp, dinv, cursor, csr_sw, E);

    // pack weights to MFMA frag order (bf16)
    k_pack_w128_2<<<128, TPB, 0, stream>>>(Wh, Wc, WhP, WcP);
    k_pack_wcell<<<1024, TPB, 0, stream>>>(Wcell, WcellP, S);

    // fp16 gather sources for x and c
    int n4 = N * 128 / 4;
    k_f32tof16_2<<<1024, TPB, 0, stream>>>(x, c, xh, ch, n4);

    int ngt = (N + 127) / 128;
    k_aggregate_h2<<<2048, TPB, 0, stream>>>(xh, ch, axb, acb, offsets, csr_sw, dinv, N);
    k_gemm_t<<<ngt, TPB, 0, stream>>>(WhP, axb, bh, nullptr, hh, N);   // h0 -> fp16 gather src
    k_gemm_t<<<ngt, TPB, 0, stream>>>(WcP, acb, bc, cbuf, nullptr, N); // c0 -> fp32 cbuf

    for (int s = 0; s < S; ++s) {
        k_aggregate_h<<<2048, TPB, 0, stream>>>(hh, acb, offsets, csr_sw, dinv, N);
        k_cell_t<<<ngt, TPB, 0, stream>>>(
            WcellP + (size_t)s * 131072, axb, acb, bcell + (size_t)s * 512,
            cbuf, hs + (size_t)s * N * 128, hh, (s == S - 1) ? hfin : nullptr, N);
    }
}